// Round 1
// baseline (1400.497 us; speedup 1.0000x reference)
//
#include <hip/hip_runtime.h>
#include <math.h>

#define VOCAB   65536
#define HDIM    512
#define MLEN    16
#define NWORDS  8192
#define IHDIM   128      // char emb dim / LSTM input
#define HHDIM   256      // hidden per direction
#define KDIM    384      // IHDIM + HHDIM

#define TM 16            // words per block (LSTM)
#define TW 16            // words per block (projection)

// workspace layout (float offsets)
#define OFF_WTF 0                            // [384][256][4] fused [Wih|Whh]^T fwd
#define OFF_WTB (OFF_WTF + 384*1024)         // same, bwd
#define OFF_BCF (OFF_WTB + 384*1024)         // [256][4] combined bias fwd
#define OFF_BCB (OFF_BCF + 1024)
#define OFF_PT  (OFF_BCB + 1024)             // [128][512][4] packed proj_w
#define OFF_CHE (OFF_PT + 512*512)           // [NWORDS][512] char-path embeddings
#define OFF_INT (OFF_CHE + NWORDS*HDIM)      // int region
// ints at OFF_INT: [0..15] cnt, [16..31] offs, [32..47] cursor, [48] total, [64..] sorted list

__device__ __forceinline__ float sigf(float x) { return 1.0f / (1.0f + __expf(-x)); }

__device__ __forceinline__ void fma4(float4& a, const float4 w, const float s) {
    a.x = fmaf(w.x, s, a.x); a.y = fmaf(w.y, s, a.y);
    a.z = fmaf(w.z, s, a.z); a.w = fmaf(w.w, s, a.w);
}

// ---- pack weights: wT[k][u][g] = (k<128 ? wih[g*256+u][k] : whh[g*256+u][k-128]) ----
__global__ void prep_k(const float* __restrict__ wihf, const float* __restrict__ whhf,
                       const float* __restrict__ bihf, const float* __restrict__ bhhf,
                       const float* __restrict__ wihb, const float* __restrict__ whhb,
                       const float* __restrict__ bihb, const float* __restrict__ bhhb,
                       const float* __restrict__ projw, float* __restrict__ ws) {
    int i = blockIdx.x * blockDim.x + threadIdx.x;
    if (i < 384 * 1024) {
        int k = i >> 10; int r = i & 1023; int u = r >> 2; int g = r & 3;
        int row = g * HHDIM + u;
        ws[OFF_WTF + i] = (k < IHDIM) ? wihf[row * IHDIM + k] : whhf[row * HHDIM + (k - IHDIM)];
        ws[OFF_WTB + i] = (k < IHDIM) ? wihb[row * IHDIM + k] : whhb[row * HHDIM + (k - IHDIM)];
    }
    if (i < 1024) {
        int u = i >> 2; int g = i & 3; int row = g * HHDIM + u;
        ws[OFF_BCF + i] = bihf[row] + bhhf[row];
        ws[OFF_BCB + i] = bihb[row] + bhhb[row];
    }
    if (i < 512 * 512) {  // pT[k4][j][kk] = projw[j][k4*4+kk]
        int k4 = i >> 11; int r = i & 2047; int j = r >> 2; int kk = r & 3;
        ws[OFF_PT + i] = projw[j * HDIM + k4 * 4 + kk];
    }
}

// ---- counting sort of OOV word indices by length (descending) ----
__global__ void count_k(const int* __restrict__ is_oov, const int* __restrict__ lens,
                        int* __restrict__ ip) {
    int n = blockIdx.x * blockDim.x + threadIdx.x;
    if (n < NWORDS && is_oov[n] > 0) atomicAdd(&ip[lens[n] - 1], 1);
}

__global__ void prefix_k(int* __restrict__ ip) {
    if (threadIdx.x == 0) {
        int total = 0;
        for (int b = 15; b >= 0; --b) { ip[16 + b] = total; ip[32 + b] = total; total += ip[b]; }
        ip[48] = total;
    }
}

__global__ void scatter_k(const int* __restrict__ is_oov, const int* __restrict__ lens,
                          int* __restrict__ ip) {
    int n = blockIdx.x * blockDim.x + threadIdx.x;
    if (n < NWORDS && is_oov[n] > 0) {
        int pos = atomicAdd(&ip[32 + lens[n] - 1], 1);
        ip[64 + pos] = n;
    }
}

// ---- fused BiLSTM: block handles TM words for one direction; thread tid = hidden unit ----
__global__ __launch_bounds__(256, 2)
void lstm_k(const int* __restrict__ char_ids, const int* __restrict__ lens,
            const float* __restrict__ char_emb, const float* __restrict__ ws,
            const int* __restrict__ ip) {
    const int dir = blockIdx.y;
    const int tid = threadIdx.x;
    const int total = ip[48];
    const int w0 = blockIdx.x * TM;
    if (w0 >= total) return;
    const int wcount = min(TM, total - w0);
    const int* sorted = ip + 64;

    __shared__ int n_s[TM];
    __shared__ int len_s[TM];
    __shared__ __align__(16) float Xs[TM][IHDIM];   // 8 KB
    __shared__ __align__(16) float Hs[TM][HHDIM];   // 16 KB

    if (tid < TM) {
        int idx = w0 + min(tid, wcount - 1);
        n_s[tid] = sorted[idx];
        len_s[tid] = (tid < wcount) ? lens[sorted[idx]] : 0;
    }
    for (int i = tid; i < TM * HHDIM; i += 256) ((float*)Hs)[i] = 0.0f;
    __syncthreads();

    int maxlen = 0;
    #pragma unroll
    for (int w = 0; w < TM; ++w) maxlen = max(maxlen, len_s[w]);

    const float4* wT4 = (const float4*)(ws + (dir ? OFF_WTB : OFF_WTF)); // wT4[k*256+u]
    const float4 bias = ((const float4*)(ws + (dir ? OFF_BCB : OFF_BCF)))[tid];

    float c_reg[TM];
    #pragma unroll
    for (int w = 0; w < TM; ++w) c_reg[w] = 0.0f;

    for (int t = 0; t < maxlen; ++t) {
        __syncthreads();   // prev compute done before overwriting Xs / after Hs writes
        // gather x_t rows (bwd: reversed within true length)
        for (int f = tid; f < TM * 32; f += 256) {
            int w = f >> 5, k4 = f & 31;
            int L = len_s[w];
            int pos = dir ? min(max(L - 1 - t, 0), MLEN - 1) : t;
            int cid = char_ids[n_s[w] * MLEN + pos];
            ((float4*)Xs[w])[k4] = ((const float4*)char_emb)[cid * 32 + k4];
        }
        __syncthreads();

        float4 acc[TM];
        #pragma unroll
        for (int w = 0; w < TM; ++w) acc[w] = bias;

        // input part: k = 0..127
        for (int k4 = 0; k4 < 32; ++k4) {
            const float4 a0 = wT4[(k4 * 4 + 0) * 256 + tid];
            const float4 a1 = wT4[(k4 * 4 + 1) * 256 + tid];
            const float4 a2 = wT4[(k4 * 4 + 2) * 256 + tid];
            const float4 a3 = wT4[(k4 * 4 + 3) * 256 + tid];
            #pragma unroll
            for (int w = 0; w < TM; ++w) {
                const float4 z = ((const float4*)Xs[w])[k4];
                fma4(acc[w], a0, z.x); fma4(acc[w], a1, z.y);
                fma4(acc[w], a2, z.z); fma4(acc[w], a3, z.w);
            }
        }
        // hidden part: k = 128..383
        for (int k4 = 0; k4 < 64; ++k4) {
            const float4 a0 = wT4[(128 + k4 * 4 + 0) * 256 + tid];
            const float4 a1 = wT4[(128 + k4 * 4 + 1) * 256 + tid];
            const float4 a2 = wT4[(128 + k4 * 4 + 2) * 256 + tid];
            const float4 a3 = wT4[(128 + k4 * 4 + 3) * 256 + tid];
            #pragma unroll
            for (int w = 0; w < TM; ++w) {
                const float4 z = ((const float4*)Hs[w])[k4];
                fma4(acc[w], a0, z.x); fma4(acc[w], a1, z.y);
                fma4(acc[w], a2, z.z); fma4(acc[w], a3, z.w);
            }
        }
        __syncthreads();   // all Hs reads done before updates
        #pragma unroll
        for (int w = 0; w < TM; ++w) {
            if (t < len_s[w]) {   // wave-uniform
                float ig = sigf(acc[w].x);
                float fg = sigf(acc[w].y);
                float gg = tanhf(acc[w].z);
                float og = sigf(acc[w].w);
                float c = fg * c_reg[w] + ig * gg;
                c_reg[w] = c;
                Hs[w][tid] = og * tanhf(c);
            }
        }
    }
    __syncthreads();
    float* che = (float*)(ws + OFF_CHE);
    for (int w = 0; w < wcount; ++w)
        che[n_s[w] * HDIM + dir * HHDIM + tid] = Hs[w][tid];
}

// ---- select (vocab vs char path) + projection ----
__global__ __launch_bounds__(256, 2)
void proj_k(const int* __restrict__ word_ids, const int* __restrict__ is_oov,
            const float* __restrict__ word_emb, const float* __restrict__ ws,
            const float* __restrict__ proj_b, float* __restrict__ out) {
    const int tid = threadIdx.x;
    const int n0 = blockIdx.x * TW;
    __shared__ __align__(16) float4 sel[TW][128];   // 32 KB

    const float* che = ws + OFF_CHE;
    for (int f = tid; f < TW * 128; f += 256) {
        int w = f >> 7, k4 = f & 127;
        int n = n0 + w;
        const float4* src = (is_oov[n] > 0) ? (const float4*)(che + (size_t)n * HDIM)
                                            : (const float4*)(word_emb + (size_t)word_ids[n] * HDIM);
        sel[w][k4] = src[k4];
    }
    __syncthreads();

    const float pb0 = proj_b[tid];
    const float pb1 = proj_b[tid + 256];
    float acc0[TW], acc1[TW];
    #pragma unroll
    for (int w = 0; w < TW; ++w) { acc0[w] = pb0; acc1[w] = pb1; }

    const float4* pT4 = (const float4*)(ws + OFF_PT);   // pT4[k4*512 + j]
    for (int k4 = 0; k4 < 128; ++k4) {
        const float4 p0 = pT4[k4 * 512 + tid];
        const float4 p1 = pT4[k4 * 512 + tid + 256];
        #pragma unroll
        for (int w = 0; w < TW; ++w) {
            const float4 z = sel[w][k4];
            acc0[w] = fmaf(p0.x, z.x, fmaf(p0.y, z.y, fmaf(p0.z, z.z, fmaf(p0.w, z.w, acc0[w]))));
            acc1[w] = fmaf(p1.x, z.x, fmaf(p1.y, z.y, fmaf(p1.z, z.z, fmaf(p1.w, z.w, acc1[w]))));
        }
    }
    #pragma unroll
    for (int w = 0; w < TW; ++w) {
        out[(size_t)(n0 + w) * HDIM + tid]       = acc0[w];
        out[(size_t)(n0 + w) * HDIM + tid + 256] = acc1[w];
    }
}

extern "C" void kernel_launch(void* const* d_in, const int* in_sizes, int n_in,
                              void* d_out, int out_size, void* d_ws, size_t ws_size,
                              hipStream_t stream) {
    const int*   word_ids  = (const int*)d_in[0];
    const int*   is_oov    = (const int*)d_in[1];
    const int*   char_ids  = (const int*)d_in[2];
    const int*   char_lens = (const int*)d_in[3];
    const float* word_emb  = (const float*)d_in[4];
    const float* char_emb  = (const float*)d_in[5];
    const float* w_ih_f    = (const float*)d_in[6];
    const float* w_hh_f    = (const float*)d_in[7];
    const float* b_ih_f    = (const float*)d_in[8];
    const float* b_hh_f    = (const float*)d_in[9];
    const float* w_ih_b    = (const float*)d_in[10];
    const float* w_hh_b    = (const float*)d_in[11];
    const float* b_ih_b    = (const float*)d_in[12];
    const float* b_hh_b    = (const float*)d_in[13];
    const float* proj_w    = (const float*)d_in[14];
    const float* proj_b    = (const float*)d_in[15];
    float* out = (float*)d_out;
    float* ws  = (float*)d_ws;
    int*   ip  = (int*)(ws + OFF_INT);

    hipMemsetAsync(ip, 0, 256, stream);   // cnt/offs/cursor/total
    prep_k<<<1536, 256, 0, stream>>>(w_ih_f, w_hh_f, b_ih_f, b_hh_f,
                                     w_ih_b, w_hh_b, b_ih_b, b_hh_b, proj_w, ws);
    count_k<<<NWORDS / 256, 256, 0, stream>>>(is_oov, char_lens, ip);
    prefix_k<<<1, 64, 0, stream>>>(ip);
    scatter_k<<<NWORDS / 256, 256, 0, stream>>>(is_oov, char_lens, ip);
    lstm_k<<<dim3(NWORDS / TM, 2), 256, 0, stream>>>(char_ids, char_lens, char_emb, ws, ip);
    proj_k<<<NWORDS / TW, 256, 0, stream>>>(word_ids, is_oov, word_emb, ws, proj_b, out);
}

// Round 2
// 1038.751 us; speedup vs baseline: 1.3483x; 1.3483x over previous
//
#include <hip/hip_runtime.h>
#include <math.h>

#define VOCAB   65536
#define HDIM    512
#define MLEN    16
#define NWORDS  8192
#define IHDIM   128      // char emb dim / LSTM input
#define HHDIM   256      // hidden per direction

#define TM 8             // words per block (LSTM)
#define TW 16            // words per block (projection)

// workspace byte offsets
#define B_WP   0u            // [2 dirs][192 k2][256 u] uint4 (4 gates f16x2) = 1572864 B
#define B_CEH  1572864u      // [256][64] uint f16x2 char emb = 65536 B
#define B_BC   1638400u      // [2][256] float4 combined bias = 8192 B
#define B_PT   1646592u      // [128][512][4] packed proj_w fp32 = 1048576 B
#define B_CHE  2695168u      // [NWORDS][512] fp32 char-path embeddings = 16777216 B
#define B_INT  19472384u     // int region: [0..15] cnt, [32..47] cursor, [48] total, [64..] sorted

typedef _Float16 h2_t __attribute__((ext_vector_type(2)));

__device__ __forceinline__ unsigned packh2(float lo, float hi) {
    union { h2_t h; unsigned u; } v;
    v.h[0] = (_Float16)lo; v.h[1] = (_Float16)hi;
    return v.u;
}
__device__ __forceinline__ h2_t as_h2(unsigned x) {
    union { unsigned u; h2_t h; } v; v.u = x; return v.h;
}

#ifndef __has_builtin
#define __has_builtin(x) 0
#endif
#if __has_builtin(__builtin_amdgcn_fdot2)
#define DOT2(a, b, c) __builtin_amdgcn_fdot2((a), (b), (c), false)
#else
__device__ __forceinline__ float DOT2(h2_t a, h2_t b, float c) {
    return c + (float)a[0] * (float)b[0] + (float)a[1] * (float)b[1];
}
#endif

__device__ __forceinline__ float sigf(float x)  { return 1.0f / (1.0f + __expf(-x)); }
__device__ __forceinline__ float tanh_f(float x){ return 1.0f - 2.0f / (__expf(2.0f * x) + 1.0f); }

// ---- pack weights to f16x2, char-emb to f16x2, combine biases, pack proj ----
__global__ void prep_k(const float* __restrict__ wihf, const float* __restrict__ whhf,
                       const float* __restrict__ bihf, const float* __restrict__ bhhf,
                       const float* __restrict__ wihb, const float* __restrict__ whhb,
                       const float* __restrict__ bihb, const float* __restrict__ bhhb,
                       const float* __restrict__ chemb, const float* __restrict__ projw,
                       char* __restrict__ wsb) {
    int i = blockIdx.x * blockDim.x + threadIdx.x;
    if (i < 98304) {  // 2 * 192 * 256 fused-weight uint4s
        int dir = i / 49152, r = i % 49152, k2 = r >> 8, u = r & 255;
        const float* wih = dir ? wihb : wihf;
        const float* whh = dir ? whhb : whhf;
        unsigned q[4];
        #pragma unroll
        for (int g = 0; g < 4; ++g) {
            int row = g * HHDIM + u;
            float lo, hi;
            if (k2 < 64) { lo = wih[row * IHDIM + 2 * k2];        hi = wih[row * IHDIM + 2 * k2 + 1]; }
            else         { lo = whh[row * HHDIM + 2 * (k2 - 64)]; hi = whh[row * HHDIM + 2 * (k2 - 64) + 1]; }
            q[g] = packh2(lo, hi);
        }
        ((uint4*)(wsb + B_WP))[i] = make_uint4(q[0], q[1], q[2], q[3]);
    }
    if (i < 16384) {  // char emb f16x2
        int cid = i >> 6, j2 = i & 63;
        ((unsigned*)(wsb + B_CEH))[i] = packh2(chemb[cid * IHDIM + 2 * j2], chemb[cid * IHDIM + 2 * j2 + 1]);
    }
    if (i < 2048) {   // combined bias [dir][u][gate]
        int dir = i >> 10, r = i & 1023, u = r >> 2, g = r & 3, row = g * HHDIM + u;
        ((float*)(wsb + B_BC))[i] = dir ? (bihb[row] + bhhb[row]) : (bihf[row] + bhhf[row]);
    }
    if (i < 262144) { // pT[k4][j][kk] = projw[j][k4*4+kk]
        int k4 = i >> 11, r = i & 2047, j = r >> 2, kk = r & 3;
        ((float*)(wsb + B_PT))[i] = projw[j * HDIM + k4 * 4 + kk];
    }
}

// ---- counting sort of OOV word indices by length (descending) ----
__global__ void count_k(const int* __restrict__ is_oov, const int* __restrict__ lens,
                        int* __restrict__ ip) {
    int n = blockIdx.x * blockDim.x + threadIdx.x;
    if (n < NWORDS && is_oov[n] > 0) atomicAdd(&ip[lens[n] - 1], 1);
}

__global__ void prefix_k(int* __restrict__ ip) {
    if (threadIdx.x == 0) {
        int total = 0;
        for (int b = 15; b >= 0; --b) { ip[16 + b] = total; ip[32 + b] = total; total += ip[b]; }
        ip[48] = total;
    }
}

__global__ void scatter_k(const int* __restrict__ is_oov, const int* __restrict__ lens,
                          int* __restrict__ ip) {
    int n = blockIdx.x * blockDim.x + threadIdx.x;
    if (n < NWORDS && is_oov[n] > 0) {
        int pos = atomicAdd(&ip[32 + lens[n] - 1], 1);
        ip[64 + pos] = n;
    }
}

// ---- fused BiLSTM: f16 dot2 gates, fp32 accum/cell; thread = hidden unit; TM words/block ----
__global__ __launch_bounds__(256, 4)
void lstm_k(const int* __restrict__ char_ids, const int* __restrict__ lens,
            const char* __restrict__ wsb, const int* __restrict__ ip) {
    const int dir = blockIdx.y;
    const int tid = threadIdx.x;
    const int total = ip[48];
    const int w0 = blockIdx.x * TM;
    if (w0 >= total) return;
    const int wcount = min(TM, total - w0);
    const int* sorted = ip + 64;

    __shared__ int n_s[TM];
    __shared__ int len_s[TM];
    __shared__ __align__(16) unsigned Zs[TM][192];  // [0..63] x f16x2, [64..191] h f16x2 — 6 KB

    if (tid < TM) {
        int idx = w0 + min(tid, wcount - 1);
        n_s[tid] = sorted[idx];
        len_s[tid] = (tid < TM ? ((tid < wcount) ? lens[sorted[idx]] : 0) : 0);
    }
    for (int i = tid; i < TM * 128; i += 256) Zs[i >> 7][64 + (i & 127)] = 0u;  // h = 0
    __syncthreads();

    int maxlen = 0;
    #pragma unroll
    for (int w = 0; w < TM; ++w) maxlen = max(maxlen, len_s[w]);

    const uint4* wp   = (const uint4*)(wsb + B_WP) + (size_t)dir * 49152;
    const uint4* ceh4 = (const uint4*)(wsb + B_CEH);
    const float4 bias = ((const float4*)(wsb + B_BC))[dir * 256 + tid];

    float c_reg[TM];
    #pragma unroll
    for (int w = 0; w < TM; ++w) c_reg[w] = 0.0f;

    // gather x_t into Zs[w][0..63] (bwd: reversed within true length)
    auto gather = [&](int t) {
        if (tid < TM * 16) {
            int w = tid >> 4, q = tid & 15;
            int L = len_s[w];
            int pos = dir ? max(L - 1 - t, 0) : t;
            int cid = char_ids[n_s[w] * MLEN + pos];
            ((uint4*)&Zs[w][0])[q] = ceh4[cid * 16 + q];
        }
    };

    gather(0);
    __syncthreads();

    for (int t = 0; t < maxlen; ++t) {
        float4 acc[TM];
        #pragma unroll
        for (int w = 0; w < TM; ++w) acc[w] = bias;

        for (int g = 0; g < 48; ++g) {
            const uint4 wq0 = wp[(g * 4 + 0) * 256 + tid];
            const uint4 wq1 = wp[(g * 4 + 1) * 256 + tid];
            const uint4 wq2 = wp[(g * 4 + 2) * 256 + tid];
            const uint4 wq3 = wp[(g * 4 + 3) * 256 + tid];
            #pragma unroll
            for (int w = 0; w < TM; ++w) {
                const uint4 z = ((const uint4*)&Zs[w][0])[g];
                const h2_t zx = as_h2(z.x), zy = as_h2(z.y), zz = as_h2(z.z), zw = as_h2(z.w);
                acc[w].x = DOT2(zx, as_h2(wq0.x), acc[w].x);
                acc[w].y = DOT2(zx, as_h2(wq0.y), acc[w].y);
                acc[w].z = DOT2(zx, as_h2(wq0.z), acc[w].z);
                acc[w].w = DOT2(zx, as_h2(wq0.w), acc[w].w);
                acc[w].x = DOT2(zy, as_h2(wq1.x), acc[w].x);
                acc[w].y = DOT2(zy, as_h2(wq1.y), acc[w].y);
                acc[w].z = DOT2(zy, as_h2(wq1.z), acc[w].z);
                acc[w].w = DOT2(zy, as_h2(wq1.w), acc[w].w);
                acc[w].x = DOT2(zz, as_h2(wq2.x), acc[w].x);
                acc[w].y = DOT2(zz, as_h2(wq2.y), acc[w].y);
                acc[w].z = DOT2(zz, as_h2(wq2.z), acc[w].z);
                acc[w].w = DOT2(zz, as_h2(wq2.w), acc[w].w);
                acc[w].x = DOT2(zw, as_h2(wq3.x), acc[w].x);
                acc[w].y = DOT2(zw, as_h2(wq3.y), acc[w].y);
                acc[w].z = DOT2(zw, as_h2(wq3.z), acc[w].z);
                acc[w].w = DOT2(zw, as_h2(wq3.w), acc[w].w);
            }
        }
        __syncthreads();   // Zs reads done before h overwrite / x overwrite

        #pragma unroll
        for (int w = 0; w < TM; ++w) {
            if (t < len_s[w]) {   // wave-uniform
                float ig = sigf(acc[w].x);
                float fg = sigf(acc[w].y);
                float gg = tanh_f(acc[w].z);
                float og = sigf(acc[w].w);
                float c = fg * c_reg[w] + ig * gg;
                c_reg[w] = c;
                ((_Float16*)&Zs[w][64])[tid] = (_Float16)(og * tanh_f(c));
            }
        }
        if (t + 1 < maxlen) gather(t + 1);   // x region disjoint from h region
        __syncthreads();
    }

    float* che = (float*)(wsb + B_CHE);
    for (int w = 0; w < wcount; ++w)
        che[(size_t)n_s[w] * HDIM + dir * HHDIM + tid] = (float)((_Float16*)&Zs[w][64])[tid];
}

// ---- select (vocab vs char path) + projection (fp32) ----
__global__ __launch_bounds__(256, 2)
void proj_k(const int* __restrict__ word_ids, const int* __restrict__ is_oov,
            const float* __restrict__ word_emb, const char* __restrict__ wsb,
            const float* __restrict__ proj_b, float* __restrict__ out) {
    const int tid = threadIdx.x;
    const int n0 = blockIdx.x * TW;
    __shared__ __align__(16) float4 sel[TW][128];   // 32 KB

    const float* che = (const float*)(wsb + B_CHE);
    for (int f = tid; f < TW * 128; f += 256) {
        int w = f >> 7, k4 = f & 127;
        int n = n0 + w;
        const float4* src = (is_oov[n] > 0) ? (const float4*)(che + (size_t)n * HDIM)
                                            : (const float4*)(word_emb + (size_t)word_ids[n] * HDIM);
        sel[w][k4] = src[k4];
    }
    __syncthreads();

    const float pb0 = proj_b[tid];
    const float pb1 = proj_b[tid + 256];
    float acc0[TW], acc1[TW];
    #pragma unroll
    for (int w = 0; w < TW; ++w) { acc0[w] = pb0; acc1[w] = pb1; }

    const float4* pT4 = (const float4*)(wsb + B_PT);   // pT4[k4*512 + j]
    for (int k4 = 0; k4 < 128; ++k4) {
        const float4 p0 = pT4[k4 * 512 + tid];
        const float4 p1 = pT4[k4 * 512 + tid + 256];
        #pragma unroll
        for (int w = 0; w < TW; ++w) {
            const float4 z = sel[w][k4];
            acc0[w] = fmaf(p0.x, z.x, fmaf(p0.y, z.y, fmaf(p0.z, z.z, fmaf(p0.w, z.w, acc0[w]))));
            acc1[w] = fmaf(p1.x, z.x, fmaf(p1.y, z.y, fmaf(p1.z, z.z, fmaf(p1.w, z.w, acc1[w]))));
        }
    }
    #pragma unroll
    for (int w = 0; w < TW; ++w) {
        out[(size_t)(n0 + w) * HDIM + tid]       = acc0[w];
        out[(size_t)(n0 + w) * HDIM + tid + 256] = acc1[w];
    }
}

extern "C" void kernel_launch(void* const* d_in, const int* in_sizes, int n_in,
                              void* d_out, int out_size, void* d_ws, size_t ws_size,
                              hipStream_t stream) {
    const int*   word_ids  = (const int*)d_in[0];
    const int*   is_oov    = (const int*)d_in[1];
    const int*   char_ids  = (const int*)d_in[2];
    const int*   char_lens = (const int*)d_in[3];
    const float* word_emb  = (const float*)d_in[4];
    const float* char_emb  = (const float*)d_in[5];
    const float* w_ih_f    = (const float*)d_in[6];
    const float* w_hh_f    = (const float*)d_in[7];
    const float* b_ih_f    = (const float*)d_in[8];
    const float* b_hh_f    = (const float*)d_in[9];
    const float* w_ih_b    = (const float*)d_in[10];
    const float* w_hh_b    = (const float*)d_in[11];
    const float* b_ih_b    = (const float*)d_in[12];
    const float* b_hh_b    = (const float*)d_in[13];
    const float* proj_w    = (const float*)d_in[14];
    const float* proj_b    = (const float*)d_in[15];
    float* out = (float*)d_out;
    char*  wsb = (char*)d_ws;
    int*   ip  = (int*)(wsb + B_INT);

    hipMemsetAsync(ip, 0, 256, stream);
    prep_k<<<1024, 256, 0, stream>>>(w_ih_f, w_hh_f, b_ih_f, b_hh_f,
                                     w_ih_b, w_hh_b, b_ih_b, b_hh_b,
                                     char_emb, proj_w, wsb);
    count_k<<<NWORDS / 256, 256, 0, stream>>>(is_oov, char_lens, ip);
    prefix_k<<<1, 64, 0, stream>>>(ip);
    scatter_k<<<NWORDS / 256, 256, 0, stream>>>(is_oov, char_lens, ip);
    lstm_k<<<dim3(NWORDS / TM, 2), 256, 0, stream>>>(char_ids, char_lens, wsb, ip);
    proj_k<<<NWORDS / TW, 256, 0, stream>>>(word_ids, is_oov, word_emb, wsb, proj_b, out);
}